// Round 2
// baseline (463.476 us; speedup 1.0000x reference)
//
#include <hip/hip_runtime.h>
#include <cstdint>
#include <cstddef>

#define EPS 1e-5f
#define DECAY 0.9f
#define SLOPE 0.01f
#define HEBB_LR 0.01f
#define WDK 1e-3f

typedef float f32x4 __attribute__((ext_vector_type(4)));
typedef __bf16 bf16x8 __attribute__((ext_vector_type(8)));
typedef unsigned short u16;
typedef unsigned int u32;

union U128 { uint4 u; bf16x8 b; };
union Pack16 { u16 s[16]; uint4 q[2]; };
union Pack8  { u16 s[8];  uint4 q; };
union Pack4  { u16 s[4];  uint2 q; };

__device__ __forceinline__ u16 f2b(float f) {            // fp32 -> bf16 RNE
  u32 u = __builtin_bit_cast(u32, f);
  u = u + 0x7FFFu + ((u >> 16) & 1u);
  return (u16)(u >> 16);
}
__device__ __forceinline__ float b2f(u16 h) {
  u32 u = ((u32)h) << 16;
  return __builtin_bit_cast(float, u);
}
__device__ __forceinline__ float wred(float x) {         // 64-lane sum
#pragma unroll
  for (int o = 32; o > 0; o >>= 1) x += __shfl_down(x, o, 64);
  return x;
}
// LDS XOR swizzle (involution): rows are 128B; spread 16B col-groups across banks
// using row bits [9:7]. Applied to BOTH the staging global source and the read addr.
__device__ __forceinline__ u32 swz(u32 b) { return b ^ (((b >> 7) & 7u) << 4); }

__device__ __forceinline__ void gld16(const u16* g, u16* lds) {
  __builtin_amdgcn_global_load_lds(
      (__attribute__((address_space(1))) void*)g,
      (__attribute__((address_space(3))) void*)lds, 16, 0, 0);
}

// ---------------- pre-LN: x_norm bf16 + inputs bf16 ----------------
__global__ __launch_bounds__(256) void prep_rows(
    const float* __restrict__ in, const float* __restrict__ pg,
    const float* __restrict__ pb, u16* __restrict__ xnb,
    u16* __restrict__ inb, int N) {
  const int row = blockIdx.x, t = threadIdx.x;
  const float* rp = in + (size_t)row * N;
  float4 v = reinterpret_cast<const float4*>(rp)[t];
  float s = v.x + v.y + v.z + v.w;
  float s2 = v.x * v.x + v.y * v.y + v.z * v.z + v.w * v.w;
  s = wred(s); s2 = wred(s2);
  __shared__ float rs_[4], rs2_[4];
  if ((t & 63) == 0) { rs_[t >> 6] = s; rs2_[t >> 6] = s2; }
  __syncthreads();
  float S = rs_[0] + rs_[1] + rs_[2] + rs_[3];
  float S2 = rs2_[0] + rs2_[1] + rs2_[2] + rs2_[3];
  float mu = S / N;
  float var = S2 / N - mu * mu;
  float rstd = rsqrtf(var + EPS);
  float4 g = reinterpret_cast<const float4*>(pg)[t];
  float4 b = reinterpret_cast<const float4*>(pb)[t];
  float xv[4] = {v.x, v.y, v.z, v.w};
  float gv[4] = {g.x, g.y, g.z, g.w};
  float bv[4] = {b.x, b.y, b.z, b.w};
  Pack4 px, pi;
#pragma unroll
  for (int j = 0; j < 4; ++j) {
    px.s[j] = f2b((xv[j] - mu) * rstd * gv[j] + bv[j]);
    pi.s[j] = f2b(xv[j]);
  }
  reinterpret_cast<uint2*>(xnb + (size_t)row * N)[t] = px.q;
  reinterpret_cast<uint2*>(inb + (size_t)row * N)[t] = pi.q;
}

// ---------------- weight convert (straight) ----------------
__global__ __launch_bounds__(256) void wconv(const float* __restrict__ W,
                                             u16* __restrict__ Wb, int total) {
  int idx = blockIdx.x * 256 + threadIdx.x;
  size_t off = (size_t)idx * 8;
  if (off >= (size_t)total) return;
  float4 a = *reinterpret_cast<const float4*>(W + off);
  float4 b = *reinterpret_cast<const float4*>(W + off + 4);
  Pack8 p;
  p.s[0] = f2b(a.x); p.s[1] = f2b(a.y); p.s[2] = f2b(a.z); p.s[3] = f2b(a.w);
  p.s[4] = f2b(b.x); p.s[5] = f2b(b.y); p.s[6] = f2b(b.z); p.s[7] = f2b(b.w);
  *reinterpret_cast<uint4*>(Wb + off) = p.q;
}

// ---------------- weight convert + transpose: Wt[c][r] = bf16(W[r][c]) -------
__global__ __launch_bounds__(256) void wconv_T(const float* __restrict__ W,
                                               u16* __restrict__ Wt, int R, int C) {
  __shared__ float tile[64][65];
  int c0 = blockIdx.x * 64, r0 = blockIdx.y * 64;
  int tr = threadIdx.x >> 2, tc = threadIdx.x & 3;
#pragma unroll
  for (int cc = 0; cc < 4; ++cc) {
    float4 v = *reinterpret_cast<const float4*>(W + (size_t)(r0 + tr) * C + c0 + tc * 16 + cc * 4);
    tile[tr][tc * 16 + cc * 4 + 0] = v.x;
    tile[tr][tc * 16 + cc * 4 + 1] = v.y;
    tile[tr][tc * 16 + cc * 4 + 2] = v.z;
    tile[tr][tc * 16 + cc * 4 + 3] = v.w;
  }
  __syncthreads();
  Pack16 p;
#pragma unroll
  for (int j = 0; j < 16; ++j) p.s[j] = f2b(tile[tc * 16 + j][tr]);
  uint4* dst = reinterpret_cast<uint4*>(Wt + (size_t)(c0 + tr) * R + r0 + tc * 16);
  dst[0] = p.q[0]; dst[1] = p.q[1];
}

// ---------------- act transpose: actT[n][b], actcT[n][b] from potential ------
__global__ __launch_bounds__(256) void transpose_act(
    const float* __restrict__ pot, const float* __restrict__ contrib,
    u16* __restrict__ actT, u16* __restrict__ actcT, int Brows, int N) {
  __shared__ float tile[64][65];
  __shared__ float csh[64];
  int n0 = blockIdx.x * 64, b0 = blockIdx.y * 64;
  int tr = threadIdx.x >> 2, tc = threadIdx.x & 3;
  if (threadIdx.x < 64) csh[threadIdx.x] = contrib[b0 + threadIdx.x];
#pragma unroll
  for (int cc = 0; cc < 4; ++cc) {
    float4 v = *reinterpret_cast<const float4*>(pot + (size_t)(b0 + tr) * N + n0 + tc * 16 + cc * 4);
    float a0 = v.x >= 0.f ? v.x : SLOPE * v.x;
    float a1 = v.y >= 0.f ? v.y : SLOPE * v.y;
    float a2 = v.z >= 0.f ? v.z : SLOPE * v.z;
    float a3 = v.w >= 0.f ? v.w : SLOPE * v.w;
    tile[tr][tc * 16 + cc * 4 + 0] = a0;
    tile[tr][tc * 16 + cc * 4 + 1] = a1;
    tile[tr][tc * 16 + cc * 4 + 2] = a2;
    tile[tr][tc * 16 + cc * 4 + 3] = a3;
  }
  __syncthreads();
  Pack16 pa, pc;
#pragma unroll
  for (int j = 0; j < 16; ++j) {
    float a = tile[tc * 16 + j][tr];
    pa.s[j] = f2b(a);
    pc.s[j] = f2b(a * csh[tc * 16 + j]);
  }
  size_t obase = (size_t)(n0 + tr) * Brows + b0 + tc * 16;
  uint4* d1 = reinterpret_cast<uint4*>(actT + obase);
  d1[0] = pa.q[0]; d1[1] = pa.q[1];
  uint4* d2 = reinterpret_cast<uint4*>(actcT + obase);
  d2[0] = pc.q[0]; d2[1] = pc.q[1];
}

// ---------------- gated residual + post-LN ----------------
__global__ __launch_bounds__(256) void fuse_out(
    const float* __restrict__ pot, const u16* __restrict__ gate,
    const float* __restrict__ in, const float* __restrict__ lg,
    const float* __restrict__ lb, float* __restrict__ out, int N) {
  const int row = blockIdx.x, t = threadIdx.x;
  size_t base = (size_t)row * N;
  float4 p = reinterpret_cast<const float4*>(pot + base)[t];
  float4 x = reinterpret_cast<const float4*>(in + base)[t];
  Pack4 gq; gq.q = reinterpret_cast<const uint2*>(gate + base)[t];
  float pv[4] = {p.x, p.y, p.z, p.w}, xv[4] = {x.x, x.y, x.z, x.w};
  float res[4];
  float s = 0.f, s2 = 0.f;
#pragma unroll
  for (int j = 0; j < 4; ++j) {
    float a = pv[j] >= 0.f ? pv[j] : SLOPE * pv[j];
    float gv = b2f(gq.s[j]);
    float r = gv * a + (1.f - gv) * xv[j];
    res[j] = r; s += r; s2 += r * r;
  }
  s = wred(s); s2 = wred(s2);
  __shared__ float rs_[4], rs2_[4];
  if ((t & 63) == 0) { rs_[t >> 6] = s; rs2_[t >> 6] = s2; }
  __syncthreads();
  float S = rs_[0] + rs_[1] + rs_[2] + rs_[3];
  float S2 = rs2_[0] + rs2_[1] + rs2_[2] + rs2_[3];
  float mu = S / N, var = S2 / N - mu * mu, rstd = rsqrtf(var + EPS);
  float4 g4 = reinterpret_cast<const float4*>(lg)[t];
  float4 b4 = reinterpret_cast<const float4*>(lb)[t];
  float gv[4] = {g4.x, g4.y, g4.z, g4.w}, bv[4] = {b4.x, b4.y, b4.z, b4.w};
  float4 o;
  o.x = (res[0] - mu) * rstd * gv[0] + bv[0];
  o.y = (res[1] - mu) * rstd * gv[1] + bv[1];
  o.z = (res[2] - mu) * rstd * gv[2] + bv[2];
  o.w = (res[3] - mu) * rstd * gv[3] + bv[3];
  reinterpret_cast<float4*>(out + base)[t] = o;
}

// ---------------- uniform MFMA GEMM: C = A[M,K] * Bt[N,K]^T ----------------
// 128x128 tile, BK=64, 4 waves (2x2), 16x16x32 bf16 MFMA, global_load_lds
// staging with pre-swizzled global source (LDS dest stays linear).
// EPI 0: potential = DECAY*prev + acc  -> outF
// EPI 1: gate bf16 = sigmoid(acc + gate_b[n]) -> outB
// EPI 2: split-K partials -> outF + bz*M*Ncols
template <int EPI>
__global__ __launch_bounds__(256) void gemm_bt(
    const u16* __restrict__ A, const u16* __restrict__ Bt,
    int lda, int kIters, int Ncols,
    const float* __restrict__ aux,
    float* __restrict__ outF,
    u16* __restrict__ outB) {
  __shared__ __align__(128) u16 lA[128 * 64];
  __shared__ __align__(128) u16 lB[128 * 64];
  const int tid = threadIdx.x;
  const int w = tid >> 6, l = tid & 63;
  const int m0 = blockIdx.y * 128, n0 = blockIdx.x * 128;
  const int kbase = blockIdx.z * kIters * 64;

  const u16* gA[4]; const u16* gB[4];
  u16* lAd[4]; u16* lBd[4];
#pragma unroll
  for (int i = 0; i < 4; ++i) {
    u32 o = (u32)(i * 4096 + w * 1024 + l * 16);   // linear LDS byte offset
    u32 op = swz(o);                               // logical (pre-swizzled source)
    int row = (int)(op >> 7);
    int kg = (int)((op >> 4) & 7u);
    gA[i] = A + (size_t)(m0 + row) * (size_t)lda + kbase + kg * 8;
    gB[i] = Bt + (size_t)(n0 + row) * (size_t)lda + kbase + kg * 8;
    lAd[i] = lA + (i * 4096 + w * 1024) / 2;       // wave-uniform dest base
    lBd[i] = lB + (i * 4096 + w * 1024) / 2;
  }

  f32x4 acc[4][4] = {};
  const int wr = w >> 1, wc = w & 1;
  const int r16 = l & 15, gq = l >> 4;
  const char* lAc = (const char*)lA;
  const char* lBc = (const char*)lB;

  for (int it = 0; it < kIters; ++it) {
    const int kk = it * 64;
#pragma unroll
    for (int i = 0; i < 4; ++i) gld16(gA[i] + kk, lAd[i]);
#pragma unroll
    for (int i = 0; i < 4; ++i) gld16(gB[i] + kk, lBd[i]);
    __syncthreads();   // compiler drains vmcnt(0) before s_barrier
#pragma unroll
    for (int ks = 0; ks < 2; ++ks) {
      U128 af[4], bfr[4];
#pragma unroll
      for (int f = 0; f < 4; ++f) {
        u32 loa = ((u32)(wr * 64 + f * 16 + r16) << 7) + (u32)(ks * 64 + gq * 16);
        af[f].u = *reinterpret_cast<const uint4*>(lAc + swz(loa));
        u32 lob = ((u32)(wc * 64 + f * 16 + r16) << 7) + (u32)(ks * 64 + gq * 16);
        bfr[f].u = *reinterpret_cast<const uint4*>(lBc + swz(lob));
      }
#pragma unroll
      for (int mf = 0; mf < 4; ++mf)
#pragma unroll
        for (int nf = 0; nf < 4; ++nf)
          acc[mf][nf] = __builtin_amdgcn_mfma_f32_16x16x32_bf16(
              af[mf].b, bfr[nf].b, acc[mf][nf], 0, 0, 0);
    }
    __syncthreads();
  }

  const size_t splitOff =
      (EPI == 2) ? (size_t)blockIdx.z * (size_t)Ncols * (size_t)(gridDim.y * 128) : 0;
#pragma unroll
  for (int mf = 0; mf < 4; ++mf) {
#pragma unroll
    for (int r = 0; r < 4; ++r) {
      const int m = m0 + wr * 64 + mf * 16 + gq * 4 + r;   // C/D row = (l>>4)*4+reg
#pragma unroll
      for (int nf = 0; nf < 4; ++nf) {
        const int n = n0 + wc * 64 + nf * 16 + r16;        // C/D col = l&15
        float v = acc[mf][nf][r];
        if (EPI == 0) {
          size_t off = (size_t)m * Ncols + n;
          outF[off] = DECAY * aux[off] + v;
        } else if (EPI == 1) {
          float gl = v + aux[n];
          outB[(size_t)m * Ncols + n] = f2b(1.f / (1.f + __expf(-gl)));
        } else {
          outF[splitOff + (size_t)m * Ncols + n] = v;
        }
      }
    }
  }
}

// ---------------- syn weight update: decay + hebb + clip ----------------
__global__ __launch_bounds__(256) void syn_update(
    const float* __restrict__ syn, const float* __restrict__ part,
    float* __restrict__ outS, int total4, float hebbScale, int nsplit) {
  int idx = blockIdx.x * 256 + threadIdx.x;
  if (idx >= total4) return;
  float4 s = reinterpret_cast<const float4*>(syn)[idx];
  float hx = 0.f, hy = 0.f, hz = 0.f, hw = 0.f;
  for (int sp = 0; sp < nsplit; ++sp) {
    float4 p = reinterpret_cast<const float4*>(part)[(size_t)sp * total4 + idx];
    hx += p.x; hy += p.y; hz += p.z; hw += p.w;
  }
  float4 o;
  o.x = fminf(1.f, fmaxf(-1.f, s.x * (1.f - WDK) + hebbScale * hx));
  o.y = fminf(1.f, fmaxf(-1.f, s.y * (1.f - WDK) + hebbScale * hy));
  o.z = fminf(1.f, fmaxf(-1.f, s.z * (1.f - WDK) + hebbScale * hz));
  o.w = fminf(1.f, fmaxf(-1.f, s.w * (1.f - WDK) + hebbScale * hw));
  reinterpret_cast<float4*>(outS)[idx] = o;
}

extern "C" void kernel_launch(void* const* d_in, const int* in_sizes, int n_in,
                              void* d_out, int out_size, void* d_ws, size_t ws_size,
                              hipStream_t stream) {
  const float* inputs        = (const float*)d_in[0];
  const float* contribution  = (const float*)d_in[1];
  const float* prev_potential= (const float*)d_in[2];
  const float* syn_weights   = (const float*)d_in[3];
  const float* gate_W        = (const float*)d_in[4];
  const float* gate_b        = (const float*)d_in[5];
  const float* pre_gamma     = (const float*)d_in[6];
  const float* pre_beta      = (const float*)d_in[7];
  const float* ln_gamma      = (const float*)d_in[8];
  const float* ln_beta       = (const float*)d_in[9];

  const int B = in_sizes[1];     // 16384
  const int N = in_sizes[5];     // 1024
  const size_t BN = (size_t)B * N;

  float* out_output = (float*)d_out;         // [B,N]
  float* out_pot    = out_output + BN;       // [B,N]
  float* out_syn    = out_output + 2 * BN;   // [N,N]

  // ws layout (~100 MB): xnorm | in_bf16 | synT | gwb | gate ; reuse after death:
  //   actT <- xnorm, actcT <- in_bf16, partials <- gate
  char* ws = (char*)d_ws;
  u16* xnb   = (u16*)ws;                                      // BN bf16
  u16* inb   = (u16*)(ws + BN * 2);                           // BN bf16
  u16* synT  = (u16*)(ws + BN * 4);                           // N*N bf16
  u16* gwb   = (u16*)(ws + BN * 4 + (size_t)N * N * 2);       // N*N bf16
  u16* gateb = (u16*)(ws + BN * 4 + (size_t)N * N * 4);       // BN bf16
  u16* actT  = xnb;
  u16* actcT = inb;
  float* part = (float*)gateb;                                // 8*N*N fp32 (32MB<=33.5MB)

  const int NS = 8;  // split-K for hebb

  prep_rows<<<B, 256, 0, stream>>>(inputs, pre_gamma, pre_beta, xnb, inb, N);
  wconv_T<<<dim3(N / 64, N / 64), 256, 0, stream>>>(syn_weights, synT, N, N);
  wconv<<<(N * N / 8 + 255) / 256, 256, 0, stream>>>(gate_W, gwb, N * N);
  gemm_bt<0><<<dim3(N / 128, B / 128), 256, 0, stream>>>(
      xnb, synT, N, N / 64, N, prev_potential, out_pot, nullptr);
  gemm_bt<1><<<dim3(N / 128, B / 128), 256, 0, stream>>>(
      inb, gwb, N, N / 64, N, gate_b, nullptr, gateb);
  fuse_out<<<B, 256, 0, stream>>>(out_pot, gateb, inputs, ln_gamma, ln_beta, out_output, N);
  transpose_act<<<dim3(N / 64, B / 64), 256, 0, stream>>>(
      out_pot, contribution, actT, actcT, B, N);
  gemm_bt<2><<<dim3(N / 128, N / 128, NS), 256, 0, stream>>>(
      actcT, actT, B, (B / 64) / NS, N, nullptr, part, nullptr);
  syn_update<<<(N * N / 4 + 255) / 256, 256, 0, stream>>>(
      syn_weights, part, out_syn, N * N / 4, HEBB_LR / (float)B, NS);
}

// Round 3
// 444.994 us; speedup vs baseline: 1.0415x; 1.0415x over previous
//
#include <hip/hip_runtime.h>
#include <cstdint>
#include <cstddef>

#define EPS 1e-5f
#define DECAY 0.9f
#define SLOPE 0.01f
#define HEBB_LR 0.01f
#define WDK 1e-3f

typedef float f32x4 __attribute__((ext_vector_type(4)));
typedef __bf16 bf16x8 __attribute__((ext_vector_type(8)));
typedef unsigned short u16;
typedef unsigned int u32;

union U128 { uint4 u; bf16x8 b; };
union Pack16 { u16 s[16]; uint4 q[2]; };
union Pack8  { u16 s[8];  uint4 q; };
union Pack4  { u16 s[4];  uint2 q; };

__device__ __forceinline__ u16 f2b(float f) {            // fp32 -> bf16 RNE
  u32 u = __builtin_bit_cast(u32, f);
  u = u + 0x7FFFu + ((u >> 16) & 1u);
  return (u16)(u >> 16);
}
__device__ __forceinline__ float b2f(u16 h) {
  u32 u = ((u32)h) << 16;
  return __builtin_bit_cast(float, u);
}
__device__ __forceinline__ float wred(float x) {         // 64-lane sum
#pragma unroll
  for (int o = 32; o > 0; o >>= 1) x += __shfl_down(x, o, 64);
  return x;
}

__device__ __forceinline__ void gld16(const u16* g, u16* lds) {
  __builtin_amdgcn_global_load_lds(
      (__attribute__((address_space(1))) void*)g,
      (__attribute__((address_space(3))) void*)lds, 16, 0, 0);
}

// ---------------- pre-LN: x_norm bf16 + inputs bf16 ----------------
__global__ __launch_bounds__(256) void prep_rows(
    const float* __restrict__ in, const float* __restrict__ pg,
    const float* __restrict__ pb, u16* __restrict__ xnb,
    u16* __restrict__ inb, int N) {
  const int row = blockIdx.x, t = threadIdx.x;
  const float* rp = in + (size_t)row * N;
  float4 v = reinterpret_cast<const float4*>(rp)[t];
  float s = v.x + v.y + v.z + v.w;
  float s2 = v.x * v.x + v.y * v.y + v.z * v.z + v.w * v.w;
  s = wred(s); s2 = wred(s2);
  __shared__ float rs_[4], rs2_[4];
  if ((t & 63) == 0) { rs_[t >> 6] = s; rs2_[t >> 6] = s2; }
  __syncthreads();
  float S = rs_[0] + rs_[1] + rs_[2] + rs_[3];
  float S2 = rs2_[0] + rs2_[1] + rs2_[2] + rs2_[3];
  float mu = S / N;
  float var = S2 / N - mu * mu;
  float rstd = rsqrtf(var + EPS);
  float4 g = reinterpret_cast<const float4*>(pg)[t];
  float4 b = reinterpret_cast<const float4*>(pb)[t];
  float xv[4] = {v.x, v.y, v.z, v.w};
  float gv[4] = {g.x, g.y, g.z, g.w};
  float bv[4] = {b.x, b.y, b.z, b.w};
  Pack4 px, pi;
#pragma unroll
  for (int j = 0; j < 4; ++j) {
    px.s[j] = f2b((xv[j] - mu) * rstd * gv[j] + bv[j]);
    pi.s[j] = f2b(xv[j]);
  }
  reinterpret_cast<uint2*>(xnb + (size_t)row * N)[t] = px.q;
  reinterpret_cast<uint2*>(inb + (size_t)row * N)[t] = pi.q;
}

// ---------------- weight convert (straight) ----------------
__global__ __launch_bounds__(256) void wconv(const float* __restrict__ W,
                                             u16* __restrict__ Wb, int total) {
  int idx = blockIdx.x * 256 + threadIdx.x;
  size_t off = (size_t)idx * 8;
  if (off >= (size_t)total) return;
  float4 a = *reinterpret_cast<const float4*>(W + off);
  float4 b = *reinterpret_cast<const float4*>(W + off + 4);
  Pack8 p;
  p.s[0] = f2b(a.x); p.s[1] = f2b(a.y); p.s[2] = f2b(a.z); p.s[3] = f2b(a.w);
  p.s[4] = f2b(b.x); p.s[5] = f2b(b.y); p.s[6] = f2b(b.z); p.s[7] = f2b(b.w);
  *reinterpret_cast<uint4*>(Wb + off) = p.q;
}

// ---------------- weight convert + transpose: Wt[c][r] = bf16(W[r][c]) -------
__global__ __launch_bounds__(256) void wconv_T(const float* __restrict__ W,
                                               u16* __restrict__ Wt, int R, int C) {
  __shared__ float tile[64][65];
  int c0 = blockIdx.x * 64, r0 = blockIdx.y * 64;
  int tr = threadIdx.x >> 2, tc = threadIdx.x & 3;
#pragma unroll
  for (int cc = 0; cc < 4; ++cc) {
    float4 v = *reinterpret_cast<const float4*>(W + (size_t)(r0 + tr) * C + c0 + tc * 16 + cc * 4);
    tile[tr][tc * 16 + cc * 4 + 0] = v.x;
    tile[tr][tc * 16 + cc * 4 + 1] = v.y;
    tile[tr][tc * 16 + cc * 4 + 2] = v.z;
    tile[tr][tc * 16 + cc * 4 + 3] = v.w;
  }
  __syncthreads();
  Pack16 p;
#pragma unroll
  for (int j = 0; j < 16; ++j) p.s[j] = f2b(tile[tc * 16 + j][tr]);
  uint4* dst = reinterpret_cast<uint4*>(Wt + (size_t)(c0 + tr) * R + r0 + tc * 16);
  dst[0] = p.q[0]; dst[1] = p.q[1];
}

// ---------------- act transpose: actT[n][b], actcT[n][b] from potential ------
__global__ __launch_bounds__(256) void transpose_act(
    const float* __restrict__ pot, const float* __restrict__ contrib,
    u16* __restrict__ actT, u16* __restrict__ actcT, int Brows, int N) {
  __shared__ float tile[64][65];
  __shared__ float csh[64];
  int n0 = blockIdx.x * 64, b0 = blockIdx.y * 64;
  int tr = threadIdx.x >> 2, tc = threadIdx.x & 3;
  if (threadIdx.x < 64) csh[threadIdx.x] = contrib[b0 + threadIdx.x];
#pragma unroll
  for (int cc = 0; cc < 4; ++cc) {
    float4 v = *reinterpret_cast<const float4*>(pot + (size_t)(b0 + tr) * N + n0 + tc * 16 + cc * 4);
    float a0 = v.x >= 0.f ? v.x : SLOPE * v.x;
    float a1 = v.y >= 0.f ? v.y : SLOPE * v.y;
    float a2 = v.z >= 0.f ? v.z : SLOPE * v.z;
    float a3 = v.w >= 0.f ? v.w : SLOPE * v.w;
    tile[tr][tc * 16 + cc * 4 + 0] = a0;
    tile[tr][tc * 16 + cc * 4 + 1] = a1;
    tile[tr][tc * 16 + cc * 4 + 2] = a2;
    tile[tr][tc * 16 + cc * 4 + 3] = a3;
  }
  __syncthreads();
  Pack16 pa, pc;
#pragma unroll
  for (int j = 0; j < 16; ++j) {
    float a = tile[tc * 16 + j][tr];
    pa.s[j] = f2b(a);
    pc.s[j] = f2b(a * csh[tc * 16 + j]);
  }
  size_t obase = (size_t)(n0 + tr) * Brows + b0 + tc * 16;
  uint4* d1 = reinterpret_cast<uint4*>(actT + obase);
  d1[0] = pa.q[0]; d1[1] = pa.q[1];
  uint4* d2 = reinterpret_cast<uint4*>(actcT + obase);
  d2[0] = pc.q[0]; d2[1] = pc.q[1];
}

// ---------------- gated residual + post-LN ----------------
__global__ __launch_bounds__(256) void fuse_out(
    const float* __restrict__ pot, const u16* __restrict__ gate,
    const float* __restrict__ in, const float* __restrict__ lg,
    const float* __restrict__ lb, float* __restrict__ out, int N) {
  const int row = blockIdx.x, t = threadIdx.x;
  size_t base = (size_t)row * N;
  float4 p = reinterpret_cast<const float4*>(pot + base)[t];
  float4 x = reinterpret_cast<const float4*>(in + base)[t];
  Pack4 gq; gq.q = reinterpret_cast<const uint2*>(gate + base)[t];
  float pv[4] = {p.x, p.y, p.z, p.w}, xv[4] = {x.x, x.y, x.z, x.w};
  float res[4];
  float s = 0.f, s2 = 0.f;
#pragma unroll
  for (int j = 0; j < 4; ++j) {
    float a = pv[j] >= 0.f ? pv[j] : SLOPE * pv[j];
    float gv = b2f(gq.s[j]);
    float r = gv * a + (1.f - gv) * xv[j];
    res[j] = r; s += r; s2 += r * r;
  }
  s = wred(s); s2 = wred(s2);
  __shared__ float rs_[4], rs2_[4];
  if ((t & 63) == 0) { rs_[t >> 6] = s; rs2_[t >> 6] = s2; }
  __syncthreads();
  float S = rs_[0] + rs_[1] + rs_[2] + rs_[3];
  float S2 = rs2_[0] + rs2_[1] + rs2_[2] + rs2_[3];
  float mu = S / N, var = S2 / N - mu * mu, rstd = rsqrtf(var + EPS);
  float4 g4 = reinterpret_cast<const float4*>(lg)[t];
  float4 b4 = reinterpret_cast<const float4*>(lb)[t];
  float gv[4] = {g4.x, g4.y, g4.z, g4.w}, bv[4] = {b4.x, b4.y, b4.z, b4.w};
  float4 o;
  o.x = (res[0] - mu) * rstd * gv[0] + bv[0];
  o.y = (res[1] - mu) * rstd * gv[1] + bv[1];
  o.z = (res[2] - mu) * rstd * gv[2] + bv[2];
  o.w = (res[3] - mu) * rstd * gv[3] + bv[3];
  reinterpret_cast<float4*>(out + base)[t] = o;
}

// ============ 256x256 8-phase MFMA GEMM: C = A[M,K] * Bt[N,K]^T ============
// 512 thr = 8 waves (2M x 4N); per-wave out 128x64; BK=64 as 2 k-slots of 32.
// LDS 128KB: slot(buf,mat,ks) = [256 rows][32 k] bf16 (16KB), row=64B.
// Swizzle: byte ^= ((byte>>7)&3)<<4  (involution; applied to pre-swizzled
// global source at stage AND to the ds_read addr -> conflict-free reads).
// Stage stream: 1 half-tile/phase, order [A_k0,B_k0,A_k1,B_k1], lead 6.
// vmcnt: 8 steady; tail 4,4,0,0 (derived: wait at phase f protects f+1).
__device__ __forceinline__ u32 swz64(u32 b) { return b ^ (((b >> 7) & 3u) << 4); }

__device__ __forceinline__ void stage8(int s, int NT4, const u16* A, const u16* Bt,
                                       int m0, int n0, int lda, int kbase,
                                       char* ldsc, int tid) {
  if (s >= NT4) return;
  const int tau = s >> 2, j = s & 3;
  const int mat = j & 1, ks = j >> 1;
  const u16* src = mat ? Bt : A;
  const int rbase = mat ? n0 : m0;
  const int kk = kbase + tau * 64 + ks * 32;
  char* dst = ldsc + (tau & 1) * 65536 + mat * 32768 + ks * 16384 + tid * 16;
  const int row = tid >> 2;
  const int kg = (tid & 3) ^ ((tid >> 3) & 3);   // pre-swizzled source k-group
  const u16* g0 = src + (size_t)(rbase + row) * (size_t)lda + kk + kg * 8;
  gld16(g0, (u16*)dst);
  gld16(g0 + (size_t)128 * (size_t)lda, (u16*)(dst + 8192));
}

#define VMW(n) asm volatile("s_waitcnt vmcnt(" #n ")" ::: "memory")
#define BARR() asm volatile("s_barrier" ::: "memory")

// EPI 0: potential = DECAY*prev + acc -> outF
// EPI 1: gate bf16 = sigmoid(acc + gate_b[n]) -> outB
// EPI 2: split-K bf16 partials -> outB + z*Ncols*M
template <int EPI>
__global__ __launch_bounds__(512, 2) void gemm8p(
    const u16* __restrict__ A, const u16* __restrict__ Bt,
    int lda, int NT, int Ncols,
    const float* __restrict__ aux,
    float* __restrict__ outF, u16* __restrict__ outB,
    int nbx, int nbxShift, int nbyX) {
  __shared__ __align__(128) u16 lds[65536];          // 128 KB
  char* ldsc = (char*)lds;
  const int tid = threadIdx.x;
  const int w = tid >> 6, l = tid & 63;
  const int wr = w >> 2, wc = w & 3;
  const int r16 = l & 15, gq = l >> 4;

  int bx, by, kb;
  if (EPI == 2) {
    bx = blockIdx.x; by = blockIdx.y; kb = blockIdx.z * NT * 64;
  } else {                                           // T1 bijective XCD decode
    int bid = blockIdx.x;
    int xcd = bid & 7, i = bid >> 3;
    by = xcd * nbyX + (i >> nbxShift);
    bx = i & (nbx - 1);
    kb = 0;
  }
  const int m0 = by * 256, n0 = bx * 256;
  const int NT4 = NT * 4;

  // per-thread swizzled ds_read offsets (slot-relative bytes)
  int pA[8], pB[4];
#pragma unroll
  for (int mf = 0; mf < 8; ++mf)
    pA[mf] = (int)swz64((u32)((wr * 128 + mf * 16 + r16) * 64 + gq * 16));
#pragma unroll
  for (int nf = 0; nf < 4; ++nf)
    pB[nf] = (int)swz64((u32)((wc * 64 + nf * 16 + r16) * 64 + gq * 16));

  f32x4 acc[8][4] = {};
  U128 af[8], bf[2];

#define LDA_(ks) { char* _b = ldsc + buf * 65536 + (ks) * 16384;              \
  _Pragma("unroll") for (int mf = 0; mf < 8; ++mf)                            \
    af[mf].u = *reinterpret_cast<const uint4*>(_b + pA[mf]); }
#define LDB_(ks, nh) { char* _b = ldsc + buf * 65536 + 32768 + (ks) * 16384;  \
  bf[0].u = *reinterpret_cast<const uint4*>(_b + pB[2 * (nh)]);               \
  bf[1].u = *reinterpret_cast<const uint4*>(_b + pB[2 * (nh) + 1]); }
#define MFMA_(nh) { __builtin_amdgcn_s_setprio(1);                            \
  _Pragma("unroll") for (int mf = 0; mf < 8; ++mf) {                          \
    acc[mf][2 * (nh)] = __builtin_amdgcn_mfma_f32_16x16x32_bf16(              \
        af[mf].b, bf[0].b, acc[mf][2 * (nh)], 0, 0, 0);                       \
    acc[mf][2 * (nh) + 1] = __builtin_amdgcn_mfma_f32_16x16x32_bf16(          \
        af[mf].b, bf[1].b, acc[mf][2 * (nh) + 1], 0, 0, 0); }                 \
  __builtin_amdgcn_s_setprio(0); }
#define STG(s) stage8((s), NT4, A, Bt, m0, n0, lda, kb, ldsc, tid)

  // prologue: stage s=0..5 (tile0 complete + tile1 k0), wait first 2 landed
  for (int s = 0; s < 6; ++s) STG(s);
  VMW(8); BARR();

  for (int t = 0; t < NT - 1; ++t) {
    const int buf = t & 1;
    const int sb = t * 4;
    LDA_(0); LDB_(0, 0); STG(sb + 6); VMW(8); BARR(); MFMA_(0); BARR();
    LDB_(0, 1);          STG(sb + 7); VMW(8); BARR(); MFMA_(1); BARR();
    LDA_(1); LDB_(1, 0); STG(sb + 8); VMW(8); BARR(); MFMA_(0); BARR();
    LDB_(1, 1);          STG(sb + 9);
    if (t == NT - 2) { VMW(4); } else { VMW(8); }
    BARR(); MFMA_(1); BARR();
  }
  { // tail tile t = NT-1 (no stages left; ks0 slots already guaranteed)
    const int buf = (NT - 1) & 1;
    LDA_(0); LDB_(0, 0); MFMA_(0);
    LDB_(0, 1);          MFMA_(1);
    VMW(0); BARR();      // everything landed globally -> ks1 slots ready
    LDA_(1); LDB_(1, 0); MFMA_(0);
    LDB_(1, 1);          MFMA_(1);
  }
#undef LDA_
#undef LDB_
#undef MFMA_
#undef STG

  const size_t splitOff =
      (EPI == 2) ? (size_t)blockIdx.z * (size_t)Ncols * (size_t)(gridDim.y * 256) : 0;
#pragma unroll
  for (int mf = 0; mf < 8; ++mf) {
#pragma unroll
    for (int r = 0; r < 4; ++r) {
      const int m = m0 + wr * 128 + mf * 16 + gq * 4 + r;  // C/D row=(l>>4)*4+reg
#pragma unroll
      for (int nf = 0; nf < 4; ++nf) {
        const int n = n0 + wc * 64 + nf * 16 + r16;        // C/D col=l&15
        float v = acc[mf][nf][r];
        if (EPI == 0) {
          size_t off = (size_t)m * Ncols + n;
          outF[off] = DECAY * aux[off] + v;
        } else if (EPI == 1) {
          float gl = v + aux[n];
          outB[(size_t)m * Ncols + n] = f2b(1.f / (1.f + __expf(-gl)));
        } else {
          outB[splitOff + (size_t)m * Ncols + n] = f2b(v);
        }
      }
    }
  }
}

// ---------------- syn weight update: decay + sum bf16 partials + clip --------
__global__ __launch_bounds__(256) void syn_update(
    const float* __restrict__ syn, const u16* __restrict__ part,
    float* __restrict__ outS, int total8, float hebbScale, int nsplit, int NN) {
  int idx = blockIdx.x * 256 + threadIdx.x;
  if (idx >= total8) return;
  float h[8] = {0.f, 0.f, 0.f, 0.f, 0.f, 0.f, 0.f, 0.f};
  for (int sp = 0; sp < nsplit; ++sp) {
    Pack8 p;
    p.q = reinterpret_cast<const uint4*>(part + (size_t)sp * NN)[idx];
#pragma unroll
    for (int j = 0; j < 8; ++j) h[j] += b2f(p.s[j]);
  }
  float4 s0 = reinterpret_cast<const float4*>(syn)[idx * 2];
  float4 s1 = reinterpret_cast<const float4*>(syn)[idx * 2 + 1];
  float sv[8] = {s0.x, s0.y, s0.z, s0.w, s1.x, s1.y, s1.z, s1.w};
  float ov[8];
#pragma unroll
  for (int j = 0; j < 8; ++j)
    ov[j] = fminf(1.f, fmaxf(-1.f, sv[j] * (1.f - WDK) + hebbScale * h[j]));
  float4 o0 = {ov[0], ov[1], ov[2], ov[3]};
  float4 o1 = {ov[4], ov[5], ov[6], ov[7]};
  reinterpret_cast<float4*>(outS)[idx * 2] = o0;
  reinterpret_cast<float4*>(outS)[idx * 2 + 1] = o1;
}

extern "C" void kernel_launch(void* const* d_in, const int* in_sizes, int n_in,
                              void* d_out, int out_size, void* d_ws, size_t ws_size,
                              hipStream_t stream) {
  const float* inputs        = (const float*)d_in[0];
  const float* contribution  = (const float*)d_in[1];
  const float* prev_potential= (const float*)d_in[2];
  const float* syn_weights   = (const float*)d_in[3];
  const float* gate_W        = (const float*)d_in[4];
  const float* gate_b        = (const float*)d_in[5];
  const float* pre_gamma     = (const float*)d_in[6];
  const float* pre_beta      = (const float*)d_in[7];
  const float* ln_gamma      = (const float*)d_in[8];
  const float* ln_beta       = (const float*)d_in[9];

  const int B = in_sizes[1];     // 16384
  const int N = in_sizes[5];     // 1024
  const size_t BN = (size_t)B * N;

  float* out_output = (float*)d_out;         // [B,N]
  float* out_pot    = out_output + BN;       // [B,N]
  float* out_syn    = out_output + 2 * BN;   // [N,N]

  // ws (~100 MB): xnorm | in_bf16 | synT | gwb | gateb ; reuse after death:
  //   actT <- xnb, actcT <- inb, bf16 partials <- gateb (16 x 2MB = 32MB)
  char* ws = (char*)d_ws;
  u16* xnb   = (u16*)ws;                                      // BN bf16
  u16* inb   = (u16*)(ws + BN * 2);                           // BN bf16
  u16* synT  = (u16*)(ws + BN * 4);                           // N*N bf16
  u16* gwb   = (u16*)(ws + BN * 4 + (size_t)N * N * 2);       // N*N bf16
  u16* gateb = (u16*)(ws + BN * 4 + (size_t)N * N * 4);       // BN bf16
  u16* actT  = xnb;
  u16* actcT = inb;
  u16* part  = gateb;

  const int NS = 16;             // hebb split-K: K=16384 -> 16 x 1024
  const int NT = N / 64;         // 16 K-steps of 64 for all three GEMMs

  prep_rows<<<B, 256, 0, stream>>>(inputs, pre_gamma, pre_beta, xnb, inb, N);
  wconv_T<<<dim3(N / 64, N / 64), 256, 0, stream>>>(syn_weights, synT, N, N);
  wconv<<<(N * N / 8 + 255) / 256, 256, 0, stream>>>(gate_W, gwb, N * N);

  const int nbx = N / 256, nbxShift = 2, nbyX = (B / 256) / 8;   // 4, 2, 8
  gemm8p<0><<<(B / 256) * (N / 256), 512, 0, stream>>>(
      xnb, synT, N, NT, N, prev_potential, out_pot, nullptr, nbx, nbxShift, nbyX);
  gemm8p<1><<<(B / 256) * (N / 256), 512, 0, stream>>>(
      inb, gwb, N, NT, N, gate_b, nullptr, gateb, nbx, nbxShift, nbyX);
  fuse_out<<<B, 256, 0, stream>>>(out_pot, gateb, inputs, ln_gamma, ln_beta, out_output, N);
  transpose_act<<<dim3(N / 64, B / 64), 256, 0, stream>>>(
      out_pot, contribution, actT, actcT, B, N);
  gemm8p<2><<<dim3(N / 256, N / 256, NS), 512, 0, stream>>>(
      actcT, actT, B, (B / NS) / 64, N, nullptr, nullptr, part, 0, 0, 0);
  syn_update<<<(N * N / 8 + 255) / 256, 256, 0, stream>>>(
      syn_weights, part, out_syn, N * N / 8, HEBB_LR / (float)B, NS, N * N);
}

// Round 4
// 437.976 us; speedup vs baseline: 1.0582x; 1.0160x over previous
//
#include <hip/hip_runtime.h>
#include <cstdint>
#include <cstddef>

#define EPS 1e-5f
#define DECAY 0.9f
#define SLOPE 0.01f
#define HEBB_LR 0.01f
#define WDK 1e-3f

typedef float f32x4 __attribute__((ext_vector_type(4)));
typedef __bf16 bf16x8 __attribute__((ext_vector_type(8)));
typedef unsigned short u16;
typedef unsigned int u32;

union U128 { uint4 u; bf16x8 b; };
union Pack16 { u16 s[16]; uint4 q[2]; };
union Pack8  { u16 s[8];  uint4 q; };
union Pack4  { u16 s[4];  uint2 q; };

__device__ __forceinline__ u16 f2b(float f) {            // fp32 -> bf16 RNE
  u32 u = __builtin_bit_cast(u32, f);
  u = u + 0x7FFFu + ((u >> 16) & 1u);
  return (u16)(u >> 16);
}
__device__ __forceinline__ float b2f(u16 h) {
  u32 u = ((u32)h) << 16;
  return __builtin_bit_cast(float, u);
}
__device__ __forceinline__ float wred(float x) {         // 64-lane sum
#pragma unroll
  for (int o = 32; o > 0; o >>= 1) x += __shfl_down(x, o, 64);
  return x;
}

__device__ __forceinline__ void gld16(const u16* g, u16* lds) {
  __builtin_amdgcn_global_load_lds(
      (__attribute__((address_space(1))) void*)g,
      (__attribute__((address_space(3))) void*)lds, 16, 0, 0);
}

// ---------------- pre-LN: x_norm bf16 + inputs bf16 ----------------
__global__ __launch_bounds__(256) void prep_rows(
    const float* __restrict__ in, const float* __restrict__ pg,
    const float* __restrict__ pb, u16* __restrict__ xnb,
    u16* __restrict__ inb, int N) {
  const int row = blockIdx.x, t = threadIdx.x;
  const float* rp = in + (size_t)row * N;
  float4 v = reinterpret_cast<const float4*>(rp)[t];
  float s = v.x + v.y + v.z + v.w;
  float s2 = v.x * v.x + v.y * v.y + v.z * v.z + v.w * v.w;
  s = wred(s); s2 = wred(s2);
  __shared__ float rs_[4], rs2_[4];
  if ((t & 63) == 0) { rs_[t >> 6] = s; rs2_[t >> 6] = s2; }
  __syncthreads();
  float S = rs_[0] + rs_[1] + rs_[2] + rs_[3];
  float S2 = rs2_[0] + rs2_[1] + rs2_[2] + rs2_[3];
  float mu = S / N;
  float var = S2 / N - mu * mu;
  float rstd = rsqrtf(var + EPS);
  float4 g = reinterpret_cast<const float4*>(pg)[t];
  float4 b = reinterpret_cast<const float4*>(pb)[t];
  float xv[4] = {v.x, v.y, v.z, v.w};
  float gv[4] = {g.x, g.y, g.z, g.w};
  float bv[4] = {b.x, b.y, b.z, b.w};
  Pack4 px, pi;
#pragma unroll
  for (int j = 0; j < 4; ++j) {
    px.s[j] = f2b((xv[j] - mu) * rstd * gv[j] + bv[j]);
    pi.s[j] = f2b(xv[j]);
  }
  reinterpret_cast<uint2*>(xnb + (size_t)row * N)[t] = px.q;
  reinterpret_cast<uint2*>(inb + (size_t)row * N)[t] = pi.q;
}

// ---------------- weight convert (straight) ----------------
__global__ __launch_bounds__(256) void wconv(const float* __restrict__ W,
                                             u16* __restrict__ Wb, int total) {
  int idx = blockIdx.x * 256 + threadIdx.x;
  size_t off = (size_t)idx * 8;
  if (off >= (size_t)total) return;
  float4 a = *reinterpret_cast<const float4*>(W + off);
  float4 b = *reinterpret_cast<const float4*>(W + off + 4);
  Pack8 p;
  p.s[0] = f2b(a.x); p.s[1] = f2b(a.y); p.s[2] = f2b(a.z); p.s[3] = f2b(a.w);
  p.s[4] = f2b(b.x); p.s[5] = f2b(b.y); p.s[6] = f2b(b.z); p.s[7] = f2b(b.w);
  *reinterpret_cast<uint4*>(Wb + off) = p.q;
}

// ---------------- weight convert + transpose: Wt[c][r] = bf16(W[r][c]) -------
__global__ __launch_bounds__(256) void wconv_T(const float* __restrict__ W,
                                               u16* __restrict__ Wt, int R, int C) {
  __shared__ float tile[64][65];
  int c0 = blockIdx.x * 64, r0 = blockIdx.y * 64;
  int tr = threadIdx.x >> 2, tc = threadIdx.x & 3;
#pragma unroll
  for (int cc = 0; cc < 4; ++cc) {
    float4 v = *reinterpret_cast<const float4*>(W + (size_t)(r0 + tr) * C + c0 + tc * 16 + cc * 4);
    tile[tr][tc * 16 + cc * 4 + 0] = v.x;
    tile[tr][tc * 16 + cc * 4 + 1] = v.y;
    tile[tr][tc * 16 + cc * 4 + 2] = v.z;
    tile[tr][tc * 16 + cc * 4 + 3] = v.w;
  }
  __syncthreads();
  Pack16 p;
#pragma unroll
  for (int j = 0; j < 16; ++j) p.s[j] = f2b(tile[tc * 16 + j][tr]);
  uint4* dst = reinterpret_cast<uint4*>(Wt + (size_t)(c0 + tr) * R + r0 + tc * 16);
  dst[0] = p.q[0]; dst[1] = p.q[1];
}

// ---------------- act transpose: actT[n][b], actcT[n][b] from potential ------
__global__ __launch_bounds__(256) void transpose_act(
    const float* __restrict__ pot, const float* __restrict__ contrib,
    u16* __restrict__ actT, u16* __restrict__ actcT, int Brows, int N) {
  __shared__ float tile[64][65];
  __shared__ float csh[64];
  int n0 = blockIdx.x * 64, b0 = blockIdx.y * 64;
  int tr = threadIdx.x >> 2, tc = threadIdx.x & 3;
  if (threadIdx.x < 64) csh[threadIdx.x] = contrib[b0 + threadIdx.x];
#pragma unroll
  for (int cc = 0; cc < 4; ++cc) {
    float4 v = *reinterpret_cast<const float4*>(pot + (size_t)(b0 + tr) * N + n0 + tc * 16 + cc * 4);
    float a0 = v.x >= 0.f ? v.x : SLOPE * v.x;
    float a1 = v.y >= 0.f ? v.y : SLOPE * v.y;
    float a2 = v.z >= 0.f ? v.z : SLOPE * v.z;
    float a3 = v.w >= 0.f ? v.w : SLOPE * v.w;
    tile[tr][tc * 16 + cc * 4 + 0] = a0;
    tile[tr][tc * 16 + cc * 4 + 1] = a1;
    tile[tr][tc * 16 + cc * 4 + 2] = a2;
    tile[tr][tc * 16 + cc * 4 + 3] = a3;
  }
  __syncthreads();
  Pack16 pa, pc;
#pragma unroll
  for (int j = 0; j < 16; ++j) {
    float a = tile[tc * 16 + j][tr];
    pa.s[j] = f2b(a);
    pc.s[j] = f2b(a * csh[tc * 16 + j]);
  }
  size_t obase = (size_t)(n0 + tr) * Brows + b0 + tc * 16;
  uint4* d1 = reinterpret_cast<uint4*>(actT + obase);
  d1[0] = pa.q[0]; d1[1] = pa.q[1];
  uint4* d2 = reinterpret_cast<uint4*>(actcT + obase);
  d2[0] = pc.q[0]; d2[1] = pc.q[1];
}

// ---------------- gated residual + post-LN (bf16 x, bf16 gate) ----------------
__global__ __launch_bounds__(256) void fuse_out(
    const float* __restrict__ pot, const u16* __restrict__ gate,
    const u16* __restrict__ inb, const float* __restrict__ lg,
    const float* __restrict__ lb, float* __restrict__ out, int N) {
  const int row = blockIdx.x, t = threadIdx.x;
  size_t base = (size_t)row * N;
  float4 p = reinterpret_cast<const float4*>(pot + base)[t];
  Pack4 xq; xq.q = reinterpret_cast<const uint2*>(inb + base)[t];
  Pack4 gq; gq.q = reinterpret_cast<const uint2*>(gate + base)[t];
  float pv[4] = {p.x, p.y, p.z, p.w};
  float res[4];
  float s = 0.f, s2 = 0.f;
#pragma unroll
  for (int j = 0; j < 4; ++j) {
    float a = pv[j] >= 0.f ? pv[j] : SLOPE * pv[j];
    float gv = b2f(gq.s[j]);
    float xv = b2f(xq.s[j]);
    float r = gv * a + (1.f - gv) * xv;
    res[j] = r; s += r; s2 += r * r;
  }
  s = wred(s); s2 = wred(s2);
  __shared__ float rs_[4], rs2_[4];
  if ((t & 63) == 0) { rs_[t >> 6] = s; rs2_[t >> 6] = s2; }
  __syncthreads();
  float S = rs_[0] + rs_[1] + rs_[2] + rs_[3];
  float S2 = rs2_[0] + rs2_[1] + rs2_[2] + rs2_[3];
  float mu = S / N, var = S2 / N - mu * mu, rstd = rsqrtf(var + EPS);
  float4 g4 = reinterpret_cast<const float4*>(lg)[t];
  float4 b4 = reinterpret_cast<const float4*>(lb)[t];
  float gv[4] = {g4.x, g4.y, g4.z, g4.w}, bv[4] = {b4.x, b4.y, b4.z, b4.w};
  float4 o;
  o.x = (res[0] - mu) * rstd * gv[0] + bv[0];
  o.y = (res[1] - mu) * rstd * gv[1] + bv[1];
  o.z = (res[2] - mu) * rstd * gv[2] + bv[2];
  o.w = (res[3] - mu) * rstd * gv[3] + bv[3];
  reinterpret_cast<float4*>(out + base)[t] = o;
}

// ============ 256x256 minimal 2-phase MFMA GEMM: C = A[M,K]*Bt[N,K]^T ========
// 512 thr = 8 waves (2M x 4N); per-wave out 128x64; BK=64; double-buffered LDS
// (2 x 64KB). ONE __syncthreads() per K-tile (its implicit vmcnt(0)+lgkmcnt(0)
// drain covers the next-tile global_load_lds issued at the top of the tile, so
// the whole 64-MFMA compute phase hides the staging latency). T3-minimum recipe.
// LDS tile layout per matrix: [256 rows][64 k] bf16, row = 128B = 8 chunks of
// 16B. Swizzle: chunk kg' = kg ^ (row&7) (involution; applied to the staging
// global source AND the ds_read addr -> 2-way-max bank aliasing, free).
// EPI 0: potential = DECAY*prev + acc -> outF
// EPI 1: gate bf16 = sigmoid(acc + gate_b[n]) -> outB
// EPI 2: split-K bf16 partials -> outB + z*Ncols*M
template <int EPI>
__global__ __launch_bounds__(512, 2) void gemm2p(
    const u16* __restrict__ A, const u16* __restrict__ Bt,
    int lda, int NT, int Ncols,
    const float* __restrict__ aux,
    float* __restrict__ outF, u16* __restrict__ outB,
    int nbx, int nbxShift, int nbyX) {
  __shared__ __align__(128) char lds[131072];          // 2 bufs x (A 32K | B 32K)
  const int tid = threadIdx.x;
  const int w = tid >> 6, l = tid & 63;
  const int wr = w >> 2, wc = w & 3;
  const int r16 = l & 15, gq = l >> 4;

  int bx, by, kb;
  if (EPI == 2) {
    bx = blockIdx.x; by = blockIdx.y; kb = blockIdx.z * NT * 64;
  } else {                                             // T1 bijective XCD decode
    int bid = blockIdx.x;
    int xcd = bid & 7, i = bid >> 3;
    by = xcd * nbyX + (i >> nbxShift);
    bx = i & (nbx - 1);
    kb = 0;
  }
  const int m0 = by * 256, n0 = bx * 256;

  // staging: 4 chunks/matrix/thread; chunk c = i*512+tid -> row=c>>3, kg=c&7;
  // source k-group pre-swizzled: kg^(row&7); LDS dest stays linear (c*16).
  const u16* gA[4]; const u16* gB[4]; int dOff[4];
#pragma unroll
  for (int i = 0; i < 4; ++i) {
    int c = i * 512 + tid;
    int row = c >> 3;
    int kg = (c & 7) ^ (row & 7);
    gA[i] = A + (size_t)(m0 + row) * (size_t)lda + kb + kg * 8;
    gB[i] = Bt + (size_t)(n0 + row) * (size_t)lda + kb + kg * 8;
    dOff[i] = c * 16;
  }

  // ds_read byte offsets: addr = row*128 + (kg ^ (row&7))*16, kg = ks*4+gq.
  // row&7 == r16&7 for both A and B fragment rows.
  int pA[8], pB[4], kgx[2];
#pragma unroll
  for (int mf = 0; mf < 8; ++mf) pA[mf] = (wr * 128 + mf * 16 + r16) * 128;
#pragma unroll
  for (int nf = 0; nf < 4; ++nf) pB[nf] = (wc * 64 + nf * 16 + r16) * 128;
  kgx[0] = ((gq) ^ (r16 & 7)) * 16;
  kgx[1] = ((4 + gq) ^ (r16 & 7)) * 16;

  f32x4 acc[8][4] = {};

#define STAGE_(t, bufb) { const int _kk = (t) * 64;                           \
  _Pragma("unroll") for (int i = 0; i < 4; ++i)                               \
    gld16(gA[i] + _kk, (u16*)(lds + (bufb) + dOff[i]));                       \
  _Pragma("unroll") for (int i = 0; i < 4; ++i)                               \
    gld16(gB[i] + _kk, (u16*)(lds + (bufb) + 32768 + dOff[i])); }

  STAGE_(0, 0);
  __syncthreads();                       // implicit vmcnt(0): buf0 ready

  int buf = 0;
  for (int t = 0; t < NT; ++t) {
    if (t + 1 < NT) STAGE_(t + 1, (buf ^ 1) * 65536);   // prefetch next tile
    const char* Ab = lds + buf * 65536;
    const char* Bb = Ab + 32768;
#pragma unroll
    for (int ks = 0; ks < 2; ++ks) {
      U128 af[8], bf[4];
#pragma unroll
      for (int mf = 0; mf < 8; ++mf)
        af[mf].u = *reinterpret_cast<const uint4*>(Ab + pA[mf] + kgx[ks]);
#pragma unroll
      for (int nf = 0; nf < 4; ++nf)
        bf[nf].u = *reinterpret_cast<const uint4*>(Bb + pB[nf] + kgx[ks]);
      __builtin_amdgcn_s_setprio(1);
#pragma unroll
      for (int mf = 0; mf < 8; ++mf)
#pragma unroll
        for (int nf = 0; nf < 4; ++nf)
          acc[mf][nf] = __builtin_amdgcn_mfma_f32_16x16x32_bf16(
              af[mf].b, bf[nf].b, acc[mf][nf], 0, 0, 0);
      __builtin_amdgcn_s_setprio(0);
    }
    __syncthreads();                     // drains vmcnt(0) -> next buf ready
    buf ^= 1;
  }
#undef STAGE_

  const size_t splitOff =
      (EPI == 2) ? (size_t)blockIdx.z * (size_t)Ncols * (size_t)(gridDim.y * 256) : 0;
#pragma unroll
  for (int mf = 0; mf < 8; ++mf) {
#pragma unroll
    for (int r = 0; r < 4; ++r) {
      const int m = m0 + wr * 128 + mf * 16 + gq * 4 + r;  // C/D row=(l>>4)*4+reg
#pragma unroll
      for (int nf = 0; nf < 4; ++nf) {
        const int n = n0 + wc * 64 + nf * 16 + r16;        // C/D col=l&15
        float v = acc[mf][nf][r];
        if (EPI == 0) {
          size_t off = (size_t)m * Ncols + n;
          outF[off] = DECAY * aux[off] + v;
        } else if (EPI == 1) {
          float gl = v + aux[n];
          outB[(size_t)m * Ncols + n] = f2b(1.f / (1.f + __expf(-gl)));
        } else {
          outB[splitOff + (size_t)m * Ncols + n] = f2b(v);
        }
      }
    }
  }
}

// ---------------- syn weight update: decay + sum bf16 partials + clip --------
__global__ __launch_bounds__(256) void syn_update(
    const float* __restrict__ syn, const u16* __restrict__ part,
    float* __restrict__ outS, int total8, float hebbScale, int nsplit, int NN) {
  int idx = blockIdx.x * 256 + threadIdx.x;
  if (idx >= total8) return;
  float h[8] = {0.f, 0.f, 0.f, 0.f, 0.f, 0.f, 0.f, 0.f};
  for (int sp = 0; sp < nsplit; ++sp) {
    Pack8 p;
    p.q = reinterpret_cast<const uint4*>(part + (size_t)sp * NN)[idx];
#pragma unroll
    for (int j = 0; j < 8; ++j) h[j] += b2f(p.s[j]);
  }
  float4 s0 = reinterpret_cast<const float4*>(syn)[idx * 2];
  float4 s1 = reinterpret_cast<const float4*>(syn)[idx * 2 + 1];
  float sv[8] = {s0.x, s0.y, s0.z, s0.w, s1.x, s1.y, s1.z, s1.w};
  float ov[8];
#pragma unroll
  for (int j = 0; j < 8; ++j)
    ov[j] = fminf(1.f, fmaxf(-1.f, sv[j] * (1.f - WDK) + hebbScale * h[j]));
  float4 o0 = {ov[0], ov[1], ov[2], ov[3]};
  float4 o1 = {ov[4], ov[5], ov[6], ov[7]};
  reinterpret_cast<float4*>(outS)[idx * 2] = o0;
  reinterpret_cast<float4*>(outS)[idx * 2 + 1] = o1;
}

extern "C" void kernel_launch(void* const* d_in, const int* in_sizes, int n_in,
                              void* d_out, int out_size, void* d_ws, size_t ws_size,
                              hipStream_t stream) {
  const float* inputs        = (const float*)d_in[0];
  const float* contribution  = (const float*)d_in[1];
  const float* prev_potential= (const float*)d_in[2];
  const float* syn_weights   = (const float*)d_in[3];
  const float* gate_W        = (const float*)d_in[4];
  const float* gate_b        = (const float*)d_in[5];
  const float* pre_gamma     = (const float*)d_in[6];
  const float* pre_beta      = (const float*)d_in[7];
  const float* ln_gamma      = (const float*)d_in[8];
  const float* ln_beta       = (const float*)d_in[9];

  const int B = in_sizes[1];     // 16384
  const int N = in_sizes[5];     // 1024
  const size_t BN = (size_t)B * N;

  float* out_output = (float*)d_out;         // [B,N]
  float* out_pot    = out_output + BN;       // [B,N]
  float* out_syn    = out_output + 2 * BN;   // [N,N]

  // ws (~100 MB): xnorm | in_bf16 | synT | gwb | gateb ; reuse after death:
  //   actT <- xnb, actcT <- inb (after fuse_out reads it), partials <- gateb
  char* ws = (char*)d_ws;
  u16* xnb   = (u16*)ws;                                      // BN bf16
  u16* inb   = (u16*)(ws + BN * 2);                           // BN bf16
  u16* synT  = (u16*)(ws + BN * 4);                           // N*N bf16
  u16* gwb   = (u16*)(ws + BN * 4 + (size_t)N * N * 2);       // N*N bf16
  u16* gateb = (u16*)(ws + BN * 4 + (size_t)N * N * 4);       // BN bf16
  u16* actT  = xnb;
  u16* actcT = inb;
  u16* part  = gateb;

  const int NS = 16;             // hebb split-K: K=16384 -> 16 x 1024
  const int NT = N / 64;         // 16 K-steps of 64 for all three GEMMs

  prep_rows<<<B, 256, 0, stream>>>(inputs, pre_gamma, pre_beta, xnb, inb, N);
  wconv_T<<<dim3(N / 64, N / 64), 256, 0, stream>>>(syn_weights, synT, N, N);
  wconv<<<(N * N / 8 + 255) / 256, 256, 0, stream>>>(gate_W, gwb, N * N);

  const int nbx = N / 256, nbxShift = 2, nbyX = (B / 256) / 8;   // 4, 2, 8
  gemm2p<0><<<(B / 256) * (N / 256), 512, 0, stream>>>(
      xnb, synT, N, NT, N, prev_potential, out_pot, nullptr, nbx, nbxShift, nbyX);
  gemm2p<1><<<(B / 256) * (N / 256), 512, 0, stream>>>(
      inb, gwb, N, NT, N, gate_b, nullptr, gateb, nbx, nbxShift, nbyX);
  fuse_out<<<B, 256, 0, stream>>>(out_pot, gateb, inb, ln_gamma, ln_beta, out_output, N);
  transpose_act<<<dim3(N / 64, B / 64), 256, 0, stream>>>(
      out_pot, contribution, actT, actcT, B, N);
  gemm2p<2><<<dim3(N / 256, N / 256, NS), 512, 0, stream>>>(
      actcT, actT, B, (B / NS) / 64, N, nullptr, nullptr, part, 0, 0, 0);
  syn_update<<<(N * N / 8 + 255) / 256, 256, 0, stream>>>(
      syn_weights, part, out_syn, N * N / 8, HEBB_LR / (float)B, NS, N * N);
}

// Round 6
// 430.247 us; speedup vs baseline: 1.0772x; 1.0180x over previous
//
#include <hip/hip_runtime.h>
#include <cstdint>
#include <cstddef>

#define EPS 1e-5f
#define DECAY 0.9f
#define SLOPE 0.01f
#define HEBB_LR 0.01f
#define WDK 1e-3f

typedef float f32x4 __attribute__((ext_vector_type(4)));
typedef __bf16 bf16x8 __attribute__((ext_vector_type(8)));
typedef unsigned short u16;
typedef unsigned int u32;

union U128 { uint4 u; bf16x8 b; };
union Pack16 { u16 s[16]; uint4 q[2]; };
union Pack8  { u16 s[8];  uint4 q; };
union Pack4  { u16 s[4];  uint2 q; };

__device__ __forceinline__ u16 f2b(float f) {            // fp32 -> bf16 RNE
  u32 u = __builtin_bit_cast(u32, f);
  u = u + 0x7FFFu + ((u >> 16) & 1u);
  return (u16)(u >> 16);
}
__device__ __forceinline__ float b2f(u16 h) {
  u32 u = ((u32)h) << 16;
  return __builtin_bit_cast(float, u);
}
__device__ __forceinline__ float wred(float x) {         // 64-lane sum
#pragma unroll
  for (int o = 32; o > 0; o >>= 1) x += __shfl_down(x, o, 64);
  return x;
}

__device__ __forceinline__ void gld16(const u16* g, const char* lds) {
  __builtin_amdgcn_global_load_lds(
      (__attribute__((address_space(1))) void*)g,
      (__attribute__((address_space(3))) void*)lds, 16, 0, 0);
}

// ---------------- pre-LN: x_norm bf16 + inputs bf16 ----------------
__global__ __launch_bounds__(256) void prep_rows(
    const float* __restrict__ in, const float* __restrict__ pg,
    const float* __restrict__ pb, u16* __restrict__ xnb,
    u16* __restrict__ inb, int N) {
  const int row = blockIdx.x, t = threadIdx.x;
  const float* rp = in + (size_t)row * N;
  float4 v = reinterpret_cast<const float4*>(rp)[t];
  float s = v.x + v.y + v.z + v.w;
  float s2 = v.x * v.x + v.y * v.y + v.z * v.z + v.w * v.w;
  s = wred(s); s2 = wred(s2);
  __shared__ float rs_[4], rs2_[4];
  if ((t & 63) == 0) { rs_[t >> 6] = s; rs2_[t >> 6] = s2; }
  __syncthreads();
  float S = rs_[0] + rs_[1] + rs_[2] + rs_[3];
  float S2 = rs2_[0] + rs2_[1] + rs2_[2] + rs2_[3];
  float mu = S / N;
  float var = S2 / N - mu * mu;
  float rstd = rsqrtf(var + EPS);
  float4 g = reinterpret_cast<const float4*>(pg)[t];
  float4 b = reinterpret_cast<const float4*>(pb)[t];
  float xv[4] = {v.x, v.y, v.z, v.w};
  float gv[4] = {g.x, g.y, g.z, g.w};
  float bv[4] = {b.x, b.y, b.z, b.w};
  Pack4 px, pi;
#pragma unroll
  for (int j = 0; j < 4; ++j) {
    px.s[j] = f2b((xv[j] - mu) * rstd * gv[j] + bv[j]);
    pi.s[j] = f2b(xv[j]);
  }
  reinterpret_cast<uint2*>(xnb + (size_t)row * N)[t] = px.q;
  reinterpret_cast<uint2*>(inb + (size_t)row * N)[t] = pi.q;
}

// ---------------- weight convert (straight) ----------------
__global__ __launch_bounds__(256) void wconv(const float* __restrict__ W,
                                             u16* __restrict__ Wb, int total) {
  int idx = blockIdx.x * 256 + threadIdx.x;
  size_t off = (size_t)idx * 8;
  if (off >= (size_t)total) return;
  float4 a = *reinterpret_cast<const float4*>(W + off);
  float4 b = *reinterpret_cast<const float4*>(W + off + 4);
  Pack8 p;
  p.s[0] = f2b(a.x); p.s[1] = f2b(a.y); p.s[2] = f2b(a.z); p.s[3] = f2b(a.w);
  p.s[4] = f2b(b.x); p.s[5] = f2b(b.y); p.s[6] = f2b(b.z); p.s[7] = f2b(b.w);
  *reinterpret_cast<uint4*>(Wb + off) = p.q;
}

// ---------------- weight convert + transpose: Wt[c][r] = bf16(W[r][c]) -------
__global__ __launch_bounds__(256) void wconv_T(const float* __restrict__ W,
                                               u16* __restrict__ Wt, int R, int C) {
  __shared__ float tile[64][65];
  int c0 = blockIdx.x * 64, r0 = blockIdx.y * 64;
  int tr = threadIdx.x >> 2, tc = threadIdx.x & 3;
#pragma unroll
  for (int cc = 0; cc < 4; ++cc) {
    float4 v = *reinterpret_cast<const float4*>(W + (size_t)(r0 + tr) * C + c0 + tc * 16 + cc * 4);
    tile[tr][tc * 16 + cc * 4 + 0] = v.x;
    tile[tr][tc * 16 + cc * 4 + 1] = v.y;
    tile[tr][tc * 16 + cc * 4 + 2] = v.z;
    tile[tr][tc * 16 + cc * 4 + 3] = v.w;
  }
  __syncthreads();
  Pack16 p;
#pragma unroll
  for (int j = 0; j < 16; ++j) p.s[j] = f2b(tile[tc * 16 + j][tr]);
  uint4* dst = reinterpret_cast<uint4*>(Wt + (size_t)(c0 + tr) * R + r0 + tc * 16);
  dst[0] = p.q[0]; dst[1] = p.q[1];
}

// ---------------- act transpose: actT[n][b], actcT[n][b] from potential ------
__global__ __launch_bounds__(256) void transpose_act(
    const float* __restrict__ pot, const float* __restrict__ contrib,
    u16* __restrict__ actT, u16* __restrict__ actcT, int Brows, int N) {
  __shared__ float tile[64][65];
  __shared__ float csh[64];
  int n0 = blockIdx.x * 64, b0 = blockIdx.y * 64;
  int tr = threadIdx.x >> 2, tc = threadIdx.x & 3;
  if (threadIdx.x < 64) csh[threadIdx.x] = contrib[b0 + threadIdx.x];
#pragma unroll
  for (int cc = 0; cc < 4; ++cc) {
    float4 v = *reinterpret_cast<const float4*>(pot + (size_t)(b0 + tr) * N + n0 + tc * 16 + cc * 4);
    float a0 = v.x >= 0.f ? v.x : SLOPE * v.x;
    float a1 = v.y >= 0.f ? v.y : SLOPE * v.y;
    float a2 = v.z >= 0.f ? v.z : SLOPE * v.z;
    float a3 = v.w >= 0.f ? v.w : SLOPE * v.w;
    tile[tr][tc * 16 + cc * 4 + 0] = a0;
    tile[tr][tc * 16 + cc * 4 + 1] = a1;
    tile[tr][tc * 16 + cc * 4 + 2] = a2;
    tile[tr][tc * 16 + cc * 4 + 3] = a3;
  }
  __syncthreads();
  Pack16 pa, pc;
#pragma unroll
  for (int j = 0; j < 16; ++j) {
    float a = tile[tc * 16 + j][tr];
    pa.s[j] = f2b(a);
    pc.s[j] = f2b(a * csh[tc * 16 + j]);
  }
  size_t obase = (size_t)(n0 + tr) * Brows + b0 + tc * 16;
  uint4* d1 = reinterpret_cast<uint4*>(actT + obase);
  d1[0] = pa.q[0]; d1[1] = pa.q[1];
  uint4* d2 = reinterpret_cast<uint4*>(actcT + obase);
  d2[0] = pc.q[0]; d2[1] = pc.q[1];
}

// ---------------- gated residual + post-LN (bf16 x, bf16 gate) ----------------
__global__ __launch_bounds__(256) void fuse_out(
    const float* __restrict__ pot, const u16* __restrict__ gate,
    const u16* __restrict__ inb, const float* __restrict__ lg,
    const float* __restrict__ lb, float* __restrict__ out, int N) {
  const int row = blockIdx.x, t = threadIdx.x;
  size_t base = (size_t)row * N;
  float4 p = reinterpret_cast<const float4*>(pot + base)[t];
  Pack4 xq; xq.q = reinterpret_cast<const uint2*>(inb + base)[t];
  Pack4 gq; gq.q = reinterpret_cast<const uint2*>(gate + base)[t];
  float pv[4] = {p.x, p.y, p.z, p.w};
  float res[4];
  float s = 0.f, s2 = 0.f;
#pragma unroll
  for (int j = 0; j < 4; ++j) {
    float a = pv[j] >= 0.f ? pv[j] : SLOPE * pv[j];
    float gv = b2f(gq.s[j]);
    float xv = b2f(xq.s[j]);
    float r = gv * a + (1.f - gv) * xv;
    res[j] = r; s += r; s2 += r * r;
  }
  s = wred(s); s2 = wred(s2);
  __shared__ float rs_[4], rs2_[4];
  if ((t & 63) == 0) { rs_[t >> 6] = s; rs2_[t >> 6] = s2; }
  __syncthreads();
  float S = rs_[0] + rs_[1] + rs_[2] + rs_[3];
  float S2 = rs2_[0] + rs2_[1] + rs2_[2] + rs2_[3];
  float mu = S / N, var = S2 / N - mu * mu, rstd = rsqrtf(var + EPS);
  float4 g4 = reinterpret_cast<const float4*>(lg)[t];
  float4 b4 = reinterpret_cast<const float4*>(lb)[t];
  float gv[4] = {g4.x, g4.y, g4.z, g4.w}, bv[4] = {b4.x, b4.y, b4.z, b4.w};
  float4 o;
  o.x = (res[0] - mu) * rstd * gv[0] + bv[0];
  o.y = (res[1] - mu) * rstd * gv[1] + bv[1];
  o.z = (res[2] - mu) * rstd * gv[2] + bv[2];
  o.w = (res[3] - mu) * rstd * gv[3] + bv[3];
  reinterpret_cast<float4*>(out + base)[t] = o;
}

// ====== 128x256-tile BK=32 MFMA GEMM, 256 thr, 2 blocks/CU: C = A*Bt^T ======
// 4 waves (2M x 2N), per-wave out 64x128 (acc 4x8 f32x4 = 128 VGPR).
// LDS 48KB: 2 bufs x (A[128][32] 8KB | B[256][32] 16KB). Memory-bound shape
// (K=1024): the lever is achieved HBM BW -> 2 blocks/CU so one block's
// compute/epilogue covers the other's staging latency + barrier drain.
// Swizzle (64B rows, 4x16B chunks): kg' = kg ^ ((row>>1)&3) -> fragment rows
// cover all 8 bank-slots of the 128B cycle (2-way = free). Applied to the
// pre-swizzled global source AND the ds_read addr (both-sides, rule #21).
// EPI 0: potential = DECAY*prev + acc -> outF
// EPI 1: gate bf16 = sigmoid(acc + gate_b[n]) -> outB
// EPI 2: split-K bf16 partials -> outB + z*Ncols*zRows
template <int EPI>
__global__ __launch_bounds__(256, 2) void gemm_w2(
    const u16* __restrict__ A, const u16* __restrict__ Bt,
    int lda, int NT, int Ncols,
    const float* __restrict__ aux,
    float* __restrict__ outF, u16* __restrict__ outB,
    int nbyX, int zPerXcd, int zRows) {
  __shared__ __align__(128) char lds[49152];           // 2 x (8K A + 16K B)
  const int tid = threadIdx.x;
  const int w = tid >> 6, l = tid & 63;
  const int wr = w >> 1, wc = w & 1;
  const int r16 = l & 15, gq = l >> 4;

  // XCD-bijective decode (grid is always 512 = 8 XCD x 64)
  int bx, by, z, kb;
  {
    const int xcd = blockIdx.x & 7, i = blockIdx.x >> 3;
    bx = i & 3;
    if (EPI == 2) {
      const int j = i >> 2;                 // 0..15
      by = j & 7;
      z = xcd * zPerXcd + (j >> 3);
      kb = z * (NT * 32);
    } else {
      by = xcd * nbyX + (i >> 2);
      z = 0; kb = 0;
    }
  }
  const int m0 = by * 128, n0 = bx * 256;

  // staging: A 2 chunks/thread, B 4 chunks/thread; chunk c -> row=c>>2, kg=c&3
  // source k-group pre-swizzled (kg ^ ((row>>1)&3)); LDS dest linear c*16.
  const u16* gA[2]; const u16* gB[4]; int dA[2], dB[4];
#pragma unroll
  for (int j = 0; j < 2; ++j) {
    int c = j * 256 + tid, row = c >> 2;
    int kg = (c & 3) ^ ((row >> 1) & 3);
    gA[j] = A + (size_t)(m0 + row) * (size_t)lda + kb + kg * 8;
    dA[j] = c * 16;
  }
#pragma unroll
  for (int j = 0; j < 4; ++j) {
    int c = j * 256 + tid, row = c >> 2;
    int kg = (c & 3) ^ ((row >> 1) & 3);
    gB[j] = Bt + (size_t)(n0 + row) * (size_t)lda + kb + kg * 8;
    dB[j] = 8192 + c * 16;
  }

  // ds_read offsets: addr = row*64 + (gq ^ ((row>>1)&3))*16; row>>1 bits
  // below 8 come only from r16, so the XOR term is r16-only.
  const int kgx = (gq ^ ((r16 >> 1) & 3)) * 16;
  int pA[4], pB[8];
#pragma unroll
  for (int mf = 0; mf < 4; ++mf) pA[mf] = (wr * 64 + mf * 16 + r16) * 64 + kgx;
#pragma unroll
  for (int nf = 0; nf < 8; ++nf) pB[nf] = 8192 + (wc * 128 + nf * 16 + r16) * 64 + kgx;

  f32x4 acc[4][8] = {};

#define STAGE_(t, bufb) { const int _kk = (t) * 32;                           \
  _Pragma("unroll") for (int j = 0; j < 2; ++j)                               \
    gld16(gA[j] + _kk, lds + (bufb) + dA[j]);                                 \
  _Pragma("unroll") for (int j = 0; j < 4; ++j)                               \
    gld16(gB[j] + _kk, lds + (bufb) + dB[j]); }

  STAGE_(0, 0);
  __syncthreads();                       // implicit vmcnt(0): buf0 ready

  int buf = 0;
  for (int t = 0; t < NT; ++t) {
    if (t + 1 < NT) STAGE_(t + 1, (buf ^ 1) * 24576);   // prefetch next tile
    const char* bb = lds + buf * 24576;
    U128 af[4], bf[8];
#pragma unroll
    for (int mf = 0; mf < 4; ++mf)
      af[mf].u = *reinterpret_cast<const uint4*>(bb + pA[mf]);
#pragma unroll
    for (int nf = 0; nf < 8; ++nf)
      bf[nf].u = *reinterpret_cast<const uint4*>(bb + pB[nf]);
    __builtin_amdgcn_s_setprio(1);
#pragma unroll
    for (int mf = 0; mf < 4; ++mf)
#pragma unroll
      for (int nf = 0; nf < 8; ++nf)
        acc[mf][nf] = __builtin_amdgcn_mfma_f32_16x16x32_bf16(
            af[mf].b, bf[nf].b, acc[mf][nf], 0, 0, 0);
    __builtin_amdgcn_s_setprio(0);
    __syncthreads();                     // drains vmcnt(0) -> next buf ready
    buf ^= 1;
  }
#undef STAGE_

  const size_t splitOff =
      (EPI == 2) ? (size_t)z * (size_t)Ncols * (size_t)zRows : 0;
#pragma unroll
  for (int mf = 0; mf < 4; ++mf) {
#pragma unroll
    for (int r = 0; r < 4; ++r) {
      const int m = m0 + wr * 64 + mf * 16 + gq * 4 + r;   // C/D row=(l>>4)*4+reg
#pragma unroll
      for (int nf = 0; nf < 8; ++nf) {
        const int n = n0 + wc * 128 + nf * 16 + r16;       // C/D col=l&15
        float v = acc[mf][nf][r];
        if (EPI == 0) {
          size_t off = (size_t)m * Ncols + n;
          outF[off] = DECAY * aux[off] + v;
        } else if (EPI == 1) {
          float gl = v + aux[n];
          outB[(size_t)m * Ncols + n] = f2b(1.f / (1.f + __expf(-gl)));
        } else {
          outB[splitOff + (size_t)m * Ncols + n] = f2b(v);
        }
      }
    }
  }
}

// ---------------- syn weight update: decay + sum bf16 partials + clip --------
__global__ __launch_bounds__(256) void syn_update(
    const float* __restrict__ syn, const u16* __restrict__ part,
    float* __restrict__ outS, int total8, float hebbScale, int nsplit, int NN) {
  int idx = blockIdx.x * 256 + threadIdx.x;
  if (idx >= total8) return;
  float h[8] = {0.f, 0.f, 0.f, 0.f, 0.f, 0.f, 0.f, 0.f};
  for (int sp = 0; sp < nsplit; ++sp) {
    Pack8 p;
    p.q = reinterpret_cast<const uint4*>(part + (size_t)sp * NN)[idx];
#pragma unroll
    for (int j = 0; j < 8; ++j) h[j] += b2f(p.s[j]);
  }
  float4 s0 = reinterpret_cast<const float4*>(syn)[idx * 2];
  float4 s1 = reinterpret_cast<const float4*>(syn)[idx * 2 + 1];
  float sv[8] = {s0.x, s0.y, s0.z, s0.w, s1.x, s1.y, s1.z, s1.w};
  float ov[8];
#pragma unroll
  for (int j = 0; j < 8; ++j)
    ov[j] = fminf(1.f, fmaxf(-1.f, sv[j] * (1.f - WDK) + hebbScale * h[j]));
  float4 o0 = {ov[0], ov[1], ov[2], ov[3]};
  float4 o1 = {ov[4], ov[5], ov[6], ov[7]};
  reinterpret_cast<float4*>(outS)[idx * 2] = o0;
  reinterpret_cast<float4*>(outS)[idx * 2 + 1] = o1;
}

extern "C" void kernel_launch(void* const* d_in, const int* in_sizes, int n_in,
                              void* d_out, int out_size, void* d_ws, size_t ws_size,
                              hipStream_t stream) {
  const float* inputs        = (const float*)d_in[0];
  const float* contribution  = (const float*)d_in[1];
  const float* prev_potential= (const float*)d_in[2];
  const float* syn_weights   = (const float*)d_in[3];
  const float* gate_W        = (const float*)d_in[4];
  const float* gate_b        = (const float*)d_in[5];
  const float* pre_gamma     = (const float*)d_in[6];
  const float* pre_beta      = (const float*)d_in[7];
  const float* ln_gamma      = (const float*)d_in[8];
  const float* ln_beta       = (const float*)d_in[9];

  const int B = in_sizes[1];     // 16384
  const int N = in_sizes[5];     // 1024
  const size_t BN = (size_t)B * N;

  float* out_output = (float*)d_out;         // [B,N]
  float* out_pot    = out_output + BN;       // [B,N]
  float* out_syn    = out_output + 2 * BN;   // [N,N]

  // ws (~100 MB): xnorm | in_bf16 | synT | gwb | gateb ; reuse after death:
  //   actT <- xnb, actcT <- inb (after fuse_out reads it), partials <- gateb
  char* ws = (char*)d_ws;
  u16* xnb   = (u16*)ws;                                      // BN bf16
  u16* inb   = (u16*)(ws + BN * 2);                           // BN bf16
  u16* synT  = (u16*)(ws + BN * 4);                           // N*N bf16
  u16* gwb   = (u16*)(ws + BN * 4 + (size_t)N * N * 2);       // N*N bf16
  u16* gateb = (u16*)(ws + BN * 4 + (size_t)N * N * 4);       // BN bf16
  u16* actT  = xnb;
  u16* actcT = inb;
  u16* part  = gateb;

  const int NS = 16;             // hebb split-K: K=16384 -> 16 x 1024
  const int NT = N / 32;         // 32 K-steps of 32 for all three GEMMs

  prep_rows<<<B, 256, 0, stream>>>(inputs, pre_gamma, pre_beta, xnb, inb, N);
  wconv_T<<<dim3(N / 64, N / 64), 256, 0, stream>>>(syn_weights, synT, N, N);
  wconv<<<(N * N / 8 + 255) / 256, 256, 0, stream>>>(gate_W, gwb, N * N);

  // grids: 512 blocks = 8 XCD x 64 = exactly 2 blocks/CU
  const int nbyX = (B / 128) / 8;              // 16 by-panels per XCD
  gemm_w2<0><<<(B / 128) * (N / 256), 256, 0, stream>>>(
      xnb, synT, N, NT, N, prev_potential, out_pot, nullptr, nbyX, 0, 0);
  gemm_w2<1><<<(B / 128) * (N / 256), 256, 0, stream>>>(
      inb, gwb, N, NT, N, gate_b, nullptr, gateb, nbyX, 0, 0);
  fuse_out<<<B, 256, 0, stream>>>(out_pot, gateb, inb, ln_gamma, ln_beta, out_output, N);
  transpose_act<<<dim3(N / 64, B / 64), 256, 0, stream>>>(
      out_pot, contribution, actT, actcT, B, N);
  gemm_w2<2><<<(N / 128) * (N / 256) * NS, 256, 0, stream>>>(
      actcT, actT, B, (B / NS) / 32, N, nullptr, nullptr, part, 0, NS / 8, N);
  syn_update<<<(N * N / 8 + 255) / 256, 256, 0, stream>>>(
      syn_weights, part, out_syn, N * N / 8, HEBB_LR / (float)B, NS, N * N);
}